// Round 10
// baseline (2334.662 us; speedup 1.0000x reference)
//
#include <hip/hip_runtime.h>
#include <hip/hip_bf16.h>

typedef __bf16 bf16x8 __attribute__((ext_vector_type(8)));
typedef float  f32x4  __attribute__((ext_vector_type(4)));
typedef float  f32x2  __attribute__((ext_vector_type(2)));
typedef unsigned short ushort_t;
static_assert(sizeof(bf16x8) == 16, "bf16x8 must be 16B");

#define DEV __device__ __forceinline__

DEV f32x4 mfma16(bf16x8 a, bf16x8 b, f32x4 c) {
    return __builtin_amdgcn_mfma_f32_16x16x32_bf16(a, b, c, 0, 0, 0);
}
DEV f32x4 mfma8(long a, long b, f32x4 c) {
    return __builtin_amdgcn_mfma_f32_16x16x32_fp8_fp8(a, b, c, 0, 0, 0);
}
DEV float sigm(float x)   { return 1.0f / (1.0f + __expf(-x)); }
DEV float tanh_f(float x) { return 2.0f / (1.0f + __expf(-2.0f * x)) - 1.0f; }

// async global->LDS, 16B per lane; lds dest = wave-uniform base + lane*16
DEV void glds16b(const unsigned char* g, unsigned char* l) {
    __builtin_amdgcn_global_load_lds(
        (const __attribute__((address_space(1))) unsigned int*)g,
        (__attribute__((address_space(3))) unsigned int*)l, 16, 0, 0);
}

DEV unsigned char f32_to_fp8(float v) {
    int p = __builtin_amdgcn_cvt_pk_fp8_f32(v, v, 0, false);
    return (unsigned char)(p & 0xFF);
}
DEV float fp8_to_f32(unsigned char b) {
    f32x2 lo = __builtin_amdgcn_cvt_pk_f32_fp8((unsigned int)b, false);
    return lo[0];
}

// ---------------- dtype detection: 1 = inputs are bf16, 0 = inputs are fp32 --
__global__ __launch_bounds__(128) void kdetect(const unsigned int* __restrict__ raw,
                                               int* __restrict__ mode) {
    __shared__ int cnt;
    if (threadIdx.x == 0) cnt = 0;
    __syncthreads();
    unsigned int w = raw[threadIdx.x];
    unsigned short lo = (unsigned short)(w & 0xFFFFu);
    unsigned int f32bits = ((unsigned int)lo) << 16;
    float v;
    __builtin_memcpy(&v, &f32bits, 4);
    float a = fabsf(v);
    if (a >= 1e-4f && a <= 1.0f) atomicAdd(&cnt, 1);
    __syncthreads();
    if (threadIdx.x == 0) *mode = (cnt >= 64) ? 1 : 0;
}

__global__ __launch_bounds__(256) void kcvt_bf16(const void* __restrict__ src,
                                                 __hip_bfloat16* __restrict__ dst,
                                                 int n, const int* __restrict__ mode) {
    int i = blockIdx.x * 256 + threadIdx.x;
    if (i >= n) return;
    if (*mode) dst[i] = ((const __hip_bfloat16*)src)[i];
    else       dst[i] = __float2bfloat16(((const float*)src)[i]);
}

__global__ __launch_bounds__(256) void kcvt_f32(const void* __restrict__ src,
                                                float* __restrict__ dst,
                                                int n, const int* __restrict__ mode) {
    int i = blockIdx.x * 256 + threadIdx.x;
    if (i >= n) return;
    if (*mode) dst[i] = __bfloat162float(((const __hip_bfloat16*)src)[i]);
    else       dst[i] = ((const float*)src)[i];
}

// --------- tiled transpose + convert: out_bf16[c][r] = (bf16)in[r][c] --------
__global__ __launch_bounds__(256) void ktranspose_cvt(const void* __restrict__ src,
                                                      __hip_bfloat16* __restrict__ out,
                                                      int R, int C,
                                                      const int* __restrict__ mode) {
    __shared__ float tile[64][65];
    int c0 = blockIdx.x * 64, r0 = blockIdx.y * 64;
    int tx = threadIdx.x & 63, ty = threadIdx.x >> 6;
    int m = *mode;
#pragma unroll
    for (int i = ty; i < 64; i += 4) {
        size_t ix = (size_t)(r0 + i) * C + (c0 + tx);
        tile[i][tx] = m ? __bfloat162float(((const __hip_bfloat16*)src)[ix])
                        : ((const float*)src)[ix];
    }
    __syncthreads();
#pragma unroll
    for (int i = ty; i < 64; i += 4)
        out[(size_t)(c0 + i) * R + (r0 + tx)] = __float2bfloat16(tile[tx][i]);
}

// --------- tiled transpose + convert to fp8 with scale -----------------------
__global__ __launch_bounds__(256) void ktranspose_cvt8(const void* __restrict__ src,
                                                       unsigned char* __restrict__ out,
                                                       int R, int C, float scale,
                                                       const int* __restrict__ mode) {
    __shared__ float tile[64][65];
    int c0 = blockIdx.x * 64, r0 = blockIdx.y * 64;
    int tx = threadIdx.x & 63, ty = threadIdx.x >> 6;
    int m = *mode;
#pragma unroll
    for (int i = ty; i < 64; i += 4) {
        size_t ix = (size_t)(r0 + i) * C + (c0 + tx);
        tile[i][tx] = m ? __bfloat162float(((const __hip_bfloat16*)src)[ix])
                        : ((const float*)src)[ix];
    }
    __syncthreads();
#pragma unroll
    for (int i = ty; i < 64; i += 4)
        out[(size_t)(c0 + i) * R + (r0 + tx)] = f32_to_fp8(tile[tx][i] * scale);
}

// ------ prep: G tables, gate-interleaved: G[dh][v][u<512][g<4] = E@Wi (+b) ---
__global__ __launch_bounds__(256) void kprep_gtab(
    const __hip_bfloat16* __restrict__ E,    // [128][128]
    const __hip_bfloat16* __restrict__ WiT,  // [2][2048][256]
    const float* __restrict__ bF,
    const float* __restrict__ bB,
    float* __restrict__ G)                   // [4][128][512][4]
{
    int dh = blockIdx.x >> 6;
    int dir = dh >> 1, half = dh & 1;
    int m0 = ((blockIdx.x >> 5) & 1) * 64;
    int n0 = (blockIdx.x & 31) * 64;
    int lane = threadIdx.x & 63, wid = threadIdx.x >> 6;
    int wrow = wid >> 1, wcol = wid & 1;
    int r16 = lane & 15, quad = lane >> 4;

    f32x4 acc[2][2] = {};
    const __hip_bfloat16* Ap = E + (size_t)(m0 + wrow * 32 + r16) * 128 + quad * 8;
    const __hip_bfloat16* Bp = WiT + (size_t)dir * 2048 * 256
                             + (size_t)(n0 + wcol * 32 + r16) * 256 + half * 128 + quad * 8;
#pragma unroll
    for (int kb = 0; kb < 128; kb += 32) {
        bf16x8 a0 = *(const bf16x8*)(Ap + kb);
        bf16x8 a1 = *(const bf16x8*)(Ap + 16 * 128 + kb);
        bf16x8 b0 = *(const bf16x8*)(Bp + kb);
        bf16x8 b1 = *(const bf16x8*)(Bp + 16 * 256 + kb);
        acc[0][0] = mfma16(a0, b0, acc[0][0]);
        acc[0][1] = mfma16(a0, b1, acc[0][1]);
        acc[1][0] = mfma16(a1, b0, acc[1][0]);
        acc[1][1] = mfma16(a1, b1, acc[1][1]);
    }
    const float* bias = dir ? bB : bF;
    float* Gt = G + (size_t)dh * 128 * 2048;
#pragma unroll
    for (int rt = 0; rt < 2; rt++)
#pragma unroll
        for (int ct = 0; ct < 2; ct++)
#pragma unroll
            for (int r = 0; r < 4; r++) {
                int mm = m0 + wrow * 32 + rt * 16 + quad * 4 + r;
                int j = n0 + wcol * 32 + ct * 16 + r16;
                float v = acc[rt][ct][r];
                if (half == 0) v += bias[j];
                int g = j >> 9, u = j & 511;
                Gt[((size_t)mm * 512 + u) * 4 + g] = v;
            }
}

// ---------------- prep: VX[t][j] = field_emb @ v_Wi + v_b --------------------
__global__ __launch_bounds__(256) void kprep_vx(
    const __hip_bfloat16* __restrict__ fe,    // [32][1024]
    const __hip_bfloat16* __restrict__ vWiT,  // [4096][1024]
    const float* __restrict__ vb,             // [4096]
    float* __restrict__ VX)                   // [32][4096]
{
    int n0 = blockIdx.x * 128;
    int lane = threadIdx.x & 63, wid = threadIdx.x >> 6;
    int r16 = lane & 15, quad = lane >> 4;
    f32x4 acc[2][2] = {};
    const __hip_bfloat16* Ap = fe + (size_t)r16 * 1024 + quad * 8;
    const __hip_bfloat16* Bp = vWiT + (size_t)(n0 + wid * 32 + r16) * 1024 + quad * 8;
    for (int kb = 0; kb < 1024; kb += 32) {
        bf16x8 a0 = *(const bf16x8*)(Ap + kb);
        bf16x8 a1 = *(const bf16x8*)(Ap + 16 * 1024 + kb);
        bf16x8 b0 = *(const bf16x8*)(Bp + kb);
        bf16x8 b1 = *(const bf16x8*)(Bp + 16 * 1024 + kb);
        acc[0][0] = mfma16(a0, b0, acc[0][0]);
        acc[0][1] = mfma16(a0, b1, acc[0][1]);
        acc[1][0] = mfma16(a1, b0, acc[1][0]);
        acc[1][1] = mfma16(a1, b1, acc[1][1]);
    }
#pragma unroll
    for (int rt = 0; rt < 2; rt++)
#pragma unroll
        for (int ct = 0; ct < 2; ct++)
#pragma unroll
            for (int r = 0; r < 4; r++) {
                int m = rt * 16 + quad * 4 + r;
                int j = n0 + wid * 32 + ct * 16 + r16;
                VX[(size_t)m * 4096 + j] = acc[rt][ct][r] + vb[j];
            }
}

// ======== encoder LSTM step (fp8): 1024 blocks (dir x 64 mt x 8 us) ==========
// m-tile 16, u-tile 64, BK=64. A = h8 (x16), B = Wh8 (x64), acc/1024.
__global__ __launch_bounds__(256, 4) void kenc_step(
    int t,
    const unsigned char* __restrict__ Wh8,    // [2][2048][512] fp8 x64
    const float* __restrict__ Gtab,           // [4][128][512][4]
    const int* __restrict__ exs,
    const int* __restrict__ cls,
    const unsigned char* __restrict__ h_in8,  // [2][1024][512] fp8 x16
    unsigned char* __restrict__ h_out8,
    float* __restrict__ c_st,                 // [2][1024][512]
    unsigned char* __restrict__ ctx8)         // [64][256][4][1024] fp8 (x16)
{
    __shared__ __align__(16) unsigned char sA[2][16 * 64];
    __shared__ __align__(16) unsigned char sB[2][256 * 64];

    int bid = blockIdx.x;
    int dir = bid >> 9;
    int mt  = (bid >> 3) & 63;
    int us  = bid & 7;
    int l = dir ? (63 - t) : t;
    int m0 = mt * 16, u0 = us * 64;

    int lane = threadIdx.x & 63, w = threadIdx.x >> 6;
    int r16 = lane & 15, quad = lane >> 4;
    int srow = lane >> 2, scol = (lane & 3) * 16;   // 16 rows/call, 64B rows

    const unsigned char* Ab = h_in8 + (size_t)dir * 1024 * 512;
    const unsigned char* Bb = Wh8 + (size_t)dir * 2048 * 512;

    f32x4 acc[4] = {};  // [gate]

    auto stage = [&](int buf, int it) {
        int kb = it * 64;
        if (w == 0)
            glds16b(Ab + (size_t)(m0 + srow) * 512 + kb + scol, &sA[buf][0]);
#pragma unroll
        for (int c = 0; c < 4; c++) {
            int rl = w * 64 + c * 16;
            int rr = rl + srow;
            int g = rr >> 6, j = rr & 63;
            glds16b(Bb + (size_t)(g * 512 + u0 + j) * 512 + kb + scol,
                    &sB[buf][rl * 64]);
        }
    };

    stage(0, 0);
    __syncthreads();
    int buf = 0;
    const int NIT = 8;  // 512/64
    for (int it = 0; it < NIT; it++) {
        if (it + 1 < NIT) stage(buf ^ 1, it + 1);
#pragma unroll
        for (int k32 = 0; k32 < 64; k32 += 32) {
            long a, bv[4];
            __builtin_memcpy(&a, &sA[buf][r16 * 64 + k32 + quad * 8], 8);
#pragma unroll
            for (int g = 0; g < 4; g++)
                __builtin_memcpy(&bv[g], &sB[buf][(g * 64 + w * 16 + r16) * 64 + k32 + quad * 8], 8);
#pragma unroll
            for (int g = 0; g < 4; g++)
                acc[g] = mfma8(a, bv[g], acc[g]);
        }
        __syncthreads();
        buf ^= 1;
    }

    // epilogue: thread owns u = u0 + w*16 + r16, 4 m's (quad*4+r)
    int u = u0 + w * 16 + r16;
    size_t cbase = (size_t)dir * 1024 * 512;
    const float* GeT = Gtab + (size_t)(dir * 2) * 128 * 2048;
    const float* GcT = GeT + 128 * 2048;
    const float S = 1.0f / 1024.0f;
#pragma unroll
    for (int r = 0; r < 4; r++) {
        int m = m0 + quad * 4 + r;
        int vE = exs[l * 1024 + m], vC = cls[l * 1024 + m];
        f32x4 ge = *(const f32x4*)&GeT[((size_t)vE * 512 + u) * 4];
        f32x4 gc = *(const f32x4*)&GcT[((size_t)vC * 512 + u) * 4];
        float gi = acc[0][r] * S + ge[0] + gc[0];
        float gf = acc[1][r] * S + ge[1] + gc[1];
        float gg = acc[2][r] * S + ge[2] + gc[2];
        float go = acc[3][r] * S + ge[3] + gc[3];
        size_t cix = cbase + (size_t)m * 512 + u;
        float cn = sigm(gf) * c_st[cix] + sigm(gi) * tanh_f(gg);
        c_st[cix] = cn;
        float hn = sigm(go) * tanh_f(cn);
        unsigned char h8 = f32_to_fp8(hn * 16.0f);
        h_out8[cix] = h8;
        ctx8[(((size_t)l * 256 + (m >> 2)) * 4 + (m & 3)) * 1024 + dir * 512 + u] = h8;
    }
}

// ---- fp8 ctx transpose: ctxT8[b4n][e][l] = ctx8[l][b4n][e] ------------------
__global__ __launch_bounds__(256) void ktrans8(const unsigned char* __restrict__ ctx8,
                                               unsigned char* __restrict__ ctxT8) {
    __shared__ unsigned int tile[64][17];
    int b4n = blockIdx.x;
    int e0 = blockIdx.y * 64;
    int tid = threadIdx.x;
#pragma unroll
    for (int pass = 0; pass < 4; pass++) {
        int idx = pass * 256 + tid;
        int l = idx >> 4, c = idx & 15;
        tile[l][c] = *(const unsigned int*)(ctx8 + (size_t)l * (1024 * 1024)
                                            + (size_t)b4n * 1024 + e0 + c * 4);
    }
    __syncthreads();
    const unsigned char* tb = (const unsigned char*)tile;
#pragma unroll
    for (int pass = 0; pass < 4; pass++) {
        int idx = pass * 256 + tid;
        int e = idx >> 4, c = idx & 15;
        unsigned int v = 0;
#pragma unroll
        for (int j = 0; j < 4; j++) {
            unsigned int byte = tb[(size_t)(c * 4 + j) * 68 + e];
            v |= byte << (8 * j);
        }
        *(unsigned int*)(ctxT8 + ((size_t)b4n * 1024 + e0 + e) * 64 + c * 4) = v;
    }
}

// ======== decoder fused GEMM (fp8): cell (0..255: 16m x 64u) + q (256..511) ==
__global__ __launch_bounds__(256, 4) void kdec_gemm(
    int t,
    const unsigned char* __restrict__ vWh8,    // [4096][1024] fp8 x64
    const unsigned char* __restrict__ Wattn8,  // [1024][1024] fp8 x64
    const float* __restrict__ VX,              // [32][4096]
    const unsigned char* __restrict__ h_in8,   // [256][1024] fp8 x16
    __hip_bfloat16* __restrict__ h_out_bf,     // hAll[t+1]
    unsigned char* __restrict__ h_out8,
    float* __restrict__ c_st,                  // [256][1024]
    float* __restrict__ qout)                  // [256][1024]
{
    __shared__ __align__(16) unsigned char sA[2][16 * 64];
    __shared__ __align__(16) unsigned char sB[2][256 * 64];

    int bid = blockIdx.x;
    int lane = threadIdx.x & 63, w = threadIdx.x >> 6;
    int r16 = lane & 15, quad = lane >> 4;
    int srow = lane >> 2, scol = (lane & 3) * 16;
    const int NIT = 16;  // 1024/64
    const float S = 1.0f / 1024.0f;

    if (bid < 256) {
        int m0 = (bid >> 4) * 16, u0 = (bid & 15) * 64;
        f32x4 acc[4] = {};
        auto stage = [&](int buf, int it) {
            int kb = it * 64;
            if (w == 0)
                glds16b(h_in8 + (size_t)(m0 + srow) * 1024 + kb + scol, &sA[buf][0]);
#pragma unroll
            for (int c = 0; c < 4; c++) {
                int rl = w * 64 + c * 16;
                int rr = rl + srow;
                int g = rr >> 6, j = rr & 63;
                glds16b(vWh8 + (size_t)(g * 1024 + u0 + j) * 1024 + kb + scol,
                        &sB[buf][rl * 64]);
            }
        };
        stage(0, 0);
        __syncthreads();
        int buf = 0;
        for (int it = 0; it < NIT; it++) {
            if (it + 1 < NIT) stage(buf ^ 1, it + 1);
#pragma unroll
            for (int k32 = 0; k32 < 64; k32 += 32) {
                long a, bv[4];
                __builtin_memcpy(&a, &sA[buf][r16 * 64 + k32 + quad * 8], 8);
#pragma unroll
                for (int g = 0; g < 4; g++)
                    __builtin_memcpy(&bv[g], &sB[buf][(g * 64 + w * 16 + r16) * 64 + k32 + quad * 8], 8);
#pragma unroll
                for (int g = 0; g < 4; g++)
                    acc[g] = mfma8(a, bv[g], acc[g]);
            }
            __syncthreads();
            buf ^= 1;
        }
        int u = u0 + w * 16 + r16;
        const float* vx = VX + (size_t)t * 4096;
        float v0 = vx[u], v1 = vx[1024 + u], v2 = vx[2048 + u], v3 = vx[3072 + u];
#pragma unroll
        for (int r = 0; r < 4; r++) {
            int m = m0 + quad * 4 + r;
            float gi = acc[0][r] * S + v0;
            float gf = acc[1][r] * S + v1;
            float gg = acc[2][r] * S + v2;
            float go = acc[3][r] * S + v3;
            size_t cix = (size_t)m * 1024 + u;
            float cn = sigm(gf) * c_st[cix] + sigm(gi) * tanh_f(gg);
            c_st[cix] = cn;
            float hn = sigm(go) * tanh_f(cn);
            h_out_bf[cix] = __float2bfloat16(hn);
            h_out8[cix] = f32_to_fp8(hn * 16.0f);
        }
    } else {
        int b2 = bid - 256;
        int m0 = (b2 >> 4) * 16, n0 = (b2 & 15) * 64;
        f32x4 acc = {};
        auto stage = [&](int buf, int it) {
            int kb = it * 64;
            if (w == 0)
                glds16b(h_in8 + (size_t)(m0 + srow) * 1024 + kb + scol, &sA[buf][0]);
            int rl = w * 16;
            glds16b(Wattn8 + (size_t)(n0 + rl + srow) * 1024 + kb + scol,
                    &sB[buf][rl * 64]);
        };
        stage(0, 0);
        __syncthreads();
        int buf = 0;
        for (int it = 0; it < NIT; it++) {
            if (it + 1 < NIT) stage(buf ^ 1, it + 1);
#pragma unroll
            for (int k32 = 0; k32 < 64; k32 += 32) {
                long a, bv;
                __builtin_memcpy(&a, &sA[buf][r16 * 64 + k32 + quad * 8], 8);
                __builtin_memcpy(&bv, &sB[buf][(w * 16 + r16) * 64 + k32 + quad * 8], 8);
                acc = mfma8(a, bv, acc);
            }
            __syncthreads();
            buf ^= 1;
        }
        int n = n0 + w * 16 + r16;
#pragma unroll
        for (int r = 0; r < 4; r++) {
            int m = m0 + quad * 4 + r;
            qout[(size_t)m * 1024 + n] = acc[r] * S;
        }
    }
}

// ======== MFMA attention: block = b, all 32 t batched (validated R9) =========
__global__ __launch_bounds__(512, 2) void kattn_mfma(
    const float* __restrict__ qall,           // [32][256][1024]
    const unsigned char* __restrict__ ctx8,   // [64][1024][1024] fp8 (x16)
    const unsigned char* __restrict__ ctxT8,  // [1024][1024][64] fp8 (x16)
    const __hip_bfloat16* __restrict__ hAll,  // [33][256][1024]
    const __hip_bfloat16* __restrict__ WcT,   // [64][2048]
    const float* __restrict__ bcomp,          // [64]
    const int* __restrict__ actions,          // [256][32]
    float* __restrict__ nllT)                 // [32][256]
{
    __shared__ __align__(16) unsigned char sQ8[32 * 1032];
    __shared__ float sS[4][32][65];
    __shared__ __align__(16) unsigned char sP[4 * 32 * 72];
    __shared__ __align__(16) ushort_t sPool[32 * 1032];
    __shared__ float slg[32 * 68];

    int b = blockIdx.x;
    int tid = threadIdx.x;
    int lane = tid & 63, w = tid >> 6;
    int r16 = lane & 15, quad = lane >> 4;
    const size_t LSTR = 1024 * 1024;

    for (int i = 0; i < 64; i++) {
        int idx = i * 512 + tid;
        int t = idx >> 10, e = idx & 1023;
        float v = qall[((size_t)t * 256 + b) * 1024 + e] * 0.25f;
        sQ8[t * 1032 + e] = f32_to_fp8(v);
    }
    __syncthreads();

    {
        int n = w >> 1, lh = w & 1;
        int l0 = lh * 32;
        f32x4 c[2][2] = {};
        const unsigned char* cbase = ctx8 + (size_t)(b * 4 + n) * 1024;
        for (int k0 = 0; k0 < 1024; k0 += 32) {
            long a[2], bv[2];
#pragma unroll
            for (int mt = 0; mt < 2; mt++)
                __builtin_memcpy(&a[mt], &sQ8[(mt * 16 + r16) * 1032 + k0 + quad * 8], 8);
#pragma unroll
            for (int lt = 0; lt < 2; lt++)
                bv[lt] = *(const long*)(cbase + (size_t)(l0 + lt * 16 + r16) * LSTR
                                        + k0 + quad * 8);
#pragma unroll
            for (int mt = 0; mt < 2; mt++)
#pragma unroll
                for (int lt = 0; lt < 2; lt++)
                    c[mt][lt] = mfma8(a[mt], bv[lt], c[mt][lt]);
        }
#pragma unroll
        for (int mt = 0; mt < 2; mt++)
#pragma unroll
            for (int lt = 0; lt < 2; lt++)
#pragma unroll
                for (int r = 0; r < 4; r++)
                    sS[n][mt * 16 + quad * 4 + r][l0 + lt * 16 + r16] = c[mt][lt][r];
    }
    __syncthreads();

    if (tid < 128) {
        int n = tid >> 5, t = tid & 31;
        const float* row = &sS[n][t][0];
        float sum = 0.f;
        for (int l = 0; l < 64; l++)
            sum += __expf(fminf(row[l] * 0.25f, 60.f));
        float inv = 16.0f / sum;
        unsigned char* pr = &sP[(n * 32 + t) * 72];
        for (int l = 0; l < 64; l++)
            pr[l] = f32_to_fp8(__expf(fminf(row[l] * 0.25f, 60.f)) * inv);
    }
    __syncthreads();

    {
        int e0 = w * 128;
        f32x4 pool[2][8];
#pragma unroll
        for (int mt = 0; mt < 2; mt++)
#pragma unroll
            for (int et = 0; et < 8; et++)
#pragma unroll
                for (int r = 0; r < 4; r++) pool[mt][et][r] = -3.4e38f;

        for (int n = 0; n < 4; n++) {
            f32x4 c[2][8] = {};
            const unsigned char* tbase = ctxT8 + (size_t)(b * 4 + n) * 1024 * 64;
#pragma unroll
            for (int k0 = 0; k0 < 64; k0 += 32) {
                long a[2];
#pragma unroll
                for (int mt = 0; mt < 2; mt++)
                    __builtin_memcpy(&a[mt], &sP[(n * 32 + mt * 16 + r16) * 72 + k0 + quad * 8], 8);
#pragma unroll
                for (int et = 0; et < 8; et++) {
                    long bv = *(const long*)(tbase + (size_t)(e0 + et * 16 + r16) * 64
                                             + k0 + quad * 8);
#pragma unroll
                    for (int mt = 0; mt < 2; mt++)
                        c[mt][et] = mfma8(a[mt], bv, c[mt][et]);
                }
            }
#pragma unroll
            for (int mt = 0; mt < 2; mt++)
#pragma unroll
                for (int et = 0; et < 8; et++)
#pragma unroll
                    for (int r = 0; r < 4; r++)
                        pool[mt][et][r] = fmaxf(pool[mt][et][r], c[mt][et][r] * (1.0f / 256.0f));
        }
#pragma unroll
        for (int mt = 0; mt < 2; mt++)
#pragma unroll
            for (int et = 0; et < 8; et++)
#pragma unroll
                for (int r = 0; r < 4; r++) {
                    int t = mt * 16 + quad * 4 + r;
                    int e = e0 + et * 16 + r16;
                    __hip_bfloat16 hb = __float2bfloat16(pool[mt][et][r]);
                    sPool[t * 1032 + e] = *(ushort_t*)&hb;
                }
    }
    __syncthreads();

    {
        int mt = w & 1, pt = w >> 1;
        f32x4 c = {};
        const __hip_bfloat16* hrow = hAll + ((size_t)(mt * 16 + r16) * 256 + b) * 1024;
        const __hip_bfloat16* wrow = WcT + (size_t)(pt * 16 + r16) * 2048;
        for (int k0 = 0; k0 < 2048; k0 += 32) {
            bf16x8 a;
            if (k0 < 1024)
                a = *(const bf16x8*)(hrow + k0 + quad * 8);
            else
                a = *(const bf16x8*)&sPool[(mt * 16 + r16) * 1032 + (k0 - 1024) + quad * 8];
            bf16x8 bv = *(const bf16x8*)(wrow + k0 + quad * 8);
            c = mfma16(a, bv, c);
        }
#pragma unroll
        for (int r = 0; r < 4; r++) {
            int t = mt * 16 + quad * 4 + r;
            int p = pt * 16 + r16;
            slg[t * 68 + p] = c[r] + bcomp[p];
        }
    }
    __syncthreads();

    if (tid < 32) {
        int t = tid;
        const float* row = &slg[t * 68];
        float m = -3.4e38f;
        for (int p = 0; p < 64; p++) m = fmaxf(m, row[p]);
        float se = 0.f;
        for (int p = 0; p < 64; p++) se += __expf(row[p] - m);
        int a = actions[b * 32 + t];
        nllT[t * 256 + b] = m + __logf(se) - row[a];
    }
}

// ---------------- decoder init: max-pool final states over io examples -------
__global__ __launch_bounds__(256) void kinit_dec(
    const unsigned char* __restrict__ hf8,  // final h8 (buf0): [2][1024][512]
    const float* __restrict__ cf,
    __hip_bfloat16* __restrict__ h0,        // hAll[0]
    unsigned char* __restrict__ h0_8,       // h8Dec[0]
    float* __restrict__ c0)
{
    int idx = blockIdx.x * 256 + threadIdx.x;
    int b = idx >> 10, e = idx & 1023;
    int dir = e >> 9, u = e & 511;
    const unsigned char* hs = hf8 + (size_t)dir * 1024 * 512;
    const float* cs = cf + (size_t)dir * 1024 * 512;
    float hv = -3.4e38f, cv = -3.4e38f;
#pragma unroll
    for (int n = 0; n < 4; n++) {
        size_t ix = (size_t)(b * 4 + n) * 512 + u;
        hv = fmaxf(hv, fp8_to_f32(hs[ix]) * 0.0625f);
        cv = fmaxf(cv, cs[ix]);
    }
    h0[idx] = __float2bfloat16(hv);
    h0_8[idx] = f32_to_fp8(hv * 16.0f);
    c0[idx] = cv;
}

__global__ void kfinal(const float* __restrict__ nllT, void* __restrict__ out,
                       const int* __restrict__ mode) {
    int i = threadIdx.x;
    float s = 0.f;
#pragma unroll
    for (int t = 0; t < 32; t++) s += nllT[t * 256 + i];
    if (*mode) ((__hip_bfloat16*)out)[i] = __float2bfloat16(s);
    else       ((float*)out)[i] = s;
}

// -----------------------------------------------------------------------------
extern "C" void kernel_launch(void* const* d_in, const int* in_sizes, int n_in,
                              void* d_out, int out_size, void* d_ws, size_t ws_size,
                              hipStream_t stream) {
    const int* exs = (const int*)d_in[0];
    const int* cls = (const int*)d_in[1];
    const void* E_raw     = d_in[2];
    const void* WiF_raw   = d_in[3];
    const void* WhF_raw   = d_in[4];
    const void* bF_raw    = d_in[5];
    const void* WiB_raw   = d_in[6];
    const void* WhB_raw   = d_in[7];
    const void* bB_raw    = d_in[8];
    const void* Wattn_raw = d_in[9];
    const void* Wcomp_raw = d_in[10];
    const void* bcomp_raw = d_in[11];
    const void* vWi_raw   = d_in[12];
    const void* vWh_raw   = d_in[13];
    const void* vb_raw    = d_in[14];
    const void* fe_raw    = d_in[15];
    const int* actions = (const int*)d_in[16];
    (void)in_sizes; (void)n_in; (void)out_size; (void)ws_size;

    char* w = (char*)d_ws;
    size_t off = 0;
    auto take = [&](size_t bytes) -> char* {
        char* p = w + off;
        off = (off + bytes + 255) & ~(size_t)255;
        return p;
    };
    unsigned char* Wh8    = (unsigned char*)take(2ull * 2048 * 512);
    unsigned char* vWh8   = (unsigned char*)take(4096ull * 1024);
    unsigned char* Wattn8 = (unsigned char*)take(1024ull * 1024);
    __hip_bfloat16* WiT   = (__hip_bfloat16*)take(2ull * 2048 * 256 * 2);
    __hip_bfloat16* vWiT  = (__hip_bfloat16*)take(4096ull * 1024 * 2);
    __hip_bfloat16* WcT   = (__hip_bfloat16*)take(64ull * 2048 * 2);
    __hip_bfloat16* Ebf   = (__hip_bfloat16*)take(128ull * 128 * 2);
    __hip_bfloat16* febf  = (__hip_bfloat16*)take(32ull * 1024 * 2);
    float* bFf   = (float*)take(2048 * 4);
    float* bBf   = (float*)take(2048 * 4);
    float* bcf   = (float*)take(64 * 4);
    float* vbf   = (float*)take(4096 * 4);
    float* Gtab  = (float*)take(4ull * 128 * 2048 * 4);
    float* VX    = (float*)take(32ull * 4096 * 4);
    unsigned char* h8Enc = (unsigned char*)take(2ull * 2 * 1024 * 512);  // [buf][dir][1024][512]
    float* cEnc = (float*)take(2ull * 1024 * 512 * 4);
    __hip_bfloat16* hAll = (__hip_bfloat16*)take(33ull * 256 * 1024 * 2);
    unsigned char* h8Dec = (unsigned char*)take(2ull * 256 * 1024);
    float* cDec = (float*)take(256ull * 1024 * 4);
    float* qall = (float*)take(32ull * 256 * 1024 * 4);
    float* nllT = (float*)take(32ull * 256 * 4);
    int*   mode = (int*)take(256);
    unsigned char* ctx8  = (unsigned char*)take(64ull * 1024 * 1024);
    unsigned char* ctxT8 = (unsigned char*)take(64ull * 1024 * 1024);

    (void)hipMemsetAsync(h8Enc, 0, 2ull * 1024 * 512, stream);  // buf0 (fp8 0 == 0.0)
    (void)hipMemsetAsync(cEnc, 0, 2ull * 1024 * 512 * 4, stream);

    kdetect<<<1, 128, 0, stream>>>((const unsigned int*)E_raw, mode);

    kcvt_bf16<<<64, 256, 0, stream>>>(E_raw,  Ebf,  128 * 128, mode);
    kcvt_bf16<<<128, 256, 0, stream>>>(fe_raw, febf, 32 * 1024, mode);
    kcvt_f32<<<8, 256, 0, stream>>>(bF_raw, bFf, 2048, mode);
    kcvt_f32<<<8, 256, 0, stream>>>(bB_raw, bBf, 2048, mode);
    kcvt_f32<<<1, 256, 0, stream>>>(bcomp_raw, bcf, 64, mode);
    kcvt_f32<<<16, 256, 0, stream>>>(vb_raw, vbf, 4096, mode);

    ktranspose_cvt8<<<dim3(32, 8),  256, 0, stream>>>(WhF_raw,   Wh8,              512, 2048, 64.f, mode);
    ktranspose_cvt8<<<dim3(32, 8),  256, 0, stream>>>(WhB_raw,   Wh8 + 2048 * 512, 512, 2048, 64.f, mode);
    ktranspose_cvt8<<<dim3(64, 16), 256, 0, stream>>>(vWh_raw,   vWh8,            1024, 4096, 64.f, mode);
    ktranspose_cvt8<<<dim3(16, 16), 256, 0, stream>>>(Wattn_raw, Wattn8,          1024, 1024, 64.f, mode);
    ktranspose_cvt<<<dim3(32, 4),  256, 0, stream>>>(WiF_raw,   WiT,              256, 2048, mode);
    ktranspose_cvt<<<dim3(32, 4),  256, 0, stream>>>(WiB_raw,   WiT + 2048 * 256, 256, 2048, mode);
    ktranspose_cvt<<<dim3(64, 16), 256, 0, stream>>>(vWi_raw,   vWiT,            1024, 4096, mode);
    ktranspose_cvt<<<dim3(1, 32),  256, 0, stream>>>(Wcomp_raw, WcT,             2048, 64,   mode);

    kprep_gtab<<<256, 256, 0, stream>>>(Ebf, WiT, bFf, bBf, Gtab);
    kprep_vx<<<32, 256, 0, stream>>>(febf, vWiT, vbf, VX);

    const size_t HB8 = 2ull * 1024 * 512;
    for (int t = 0; t < 64; t++) {
        kenc_step<<<1024, 256, 0, stream>>>(t, Wh8, Gtab, exs, cls,
                                            h8Enc + (size_t)(t & 1) * HB8,
                                            h8Enc + (size_t)((t + 1) & 1) * HB8,
                                            cEnc, ctx8);
    }
    ktrans8<<<dim3(1024, 16), 256, 0, stream>>>(ctx8, ctxT8);
    kinit_dec<<<1024, 256, 0, stream>>>(h8Enc, cEnc, hAll, h8Dec, cDec);

    const size_t HD = 256ull * 1024;
    for (int t = 0; t < 32; t++) {
        kdec_gemm<<<512, 256, 0, stream>>>(t, vWh8, Wattn8, VX,
                                           h8Dec + (size_t)(t & 1) * HD,
                                           hAll + (size_t)(t + 1) * HD,
                                           h8Dec + (size_t)((t + 1) & 1) * HD,
                                           cDec, qall + (size_t)t * HD);
    }
    kattn_mfma<<<256, 512, 0, stream>>>(qall, ctx8, ctxT8, hAll, WcT, bcf,
                                        actions, nllT);
    kfinal<<<1, 256, 0, stream>>>(nllT, d_out, mode);
}